// Round 3
// baseline (110.329 us; speedup 1.0000x reference)
//
#include <hip/hip_runtime.h>
#include <math.h>

// Problem constants (fixed shapes from reference)
#define B_ 2
#define N_ 16384
#define M_ 12000
#define F_ 16384

#define P_ 128          // face partitions (argmin granularity)
#define TILE_ 128       // faces per partition
#define NCHUNK_ 8       // face chunks (knn blocks per vert-block)

typedef short bf16x8 __attribute__((ext_vector_type(8)));
typedef float f32x16 __attribute__((ext_vector_type(16)));

__device__ __host__ inline unsigned short bf16rn(float x) {
  unsigned int u = __float_as_uint(x);
  u = (u + 0x7FFFu + ((u >> 16) & 1u)) >> 16;
  return (unsigned short)u;
}
__device__ inline float bf16tof(unsigned short h) {
  return __uint_as_float(((unsigned int)h) << 16);
}

// async global->LDS, 16B per lane. LDS dest must be wave-uniform base;
// HW writes base + lane*16 (linear). Global src is per-lane.
__device__ __forceinline__ void gload_lds16(const uint4* g, uint4* l) {
  __builtin_amdgcn_global_load_lds(
      (const __attribute__((address_space(1))) void*)g,
      (__attribute__((address_space(3))) void*)l, 16, 0, 0);
}

// ---------------------------------------------------------------------------
// Kernel A: per-face precompute + out[0] zero-init.
// Round 12: grid 256x128 (was 128x256) -> all 256 CUs host gather waves.
//   fcurr[f] = (centroid_curr.xyz, |centroid_curr|^2)   (exact fp32 chain)
//   fnext[2f] = centroid_next, fnext[2f+1] = unit normal
//   fpack[f]  = 16 bf16 (32B): K=16 A-operand for mfma_32x32x16 (hi/lo
//   product trick: (fhi+flo)*(chi+clo) per coordinate)
// ---------------------------------------------------------------------------
__global__ __launch_bounds__(128) void face_precomp(
    const float* __restrict__ obs_curr,
    const float* __restrict__ obs_next,
    const int* __restrict__ faces,
    float4* __restrict__ fcurr,
    float4* __restrict__ fnext,
    uint4* __restrict__ fpack,
    float* __restrict__ out) {
  int t = blockIdx.x * 128 + threadIdx.x;
  if (t == 0) out[0] = 0.0f;  // epilogue (later, same stream) accumulates
  if (t >= B_ * F_) return;
  int b = t / F_;
  const float* oc = obs_curr + (size_t)b * M_ * 3;
  const float* on = obs_next + (size_t)b * M_ * 3;
  int i0 = faces[3 * (size_t)t + 0];
  int i1 = faces[3 * (size_t)t + 1];
  int i2 = faces[3 * (size_t)t + 2];

  float ax = oc[3*i0], ay = oc[3*i0+1], az = oc[3*i0+2];
  float bx = oc[3*i1], by = oc[3*i1+1], bz = oc[3*i1+2];
  float cx = oc[3*i2], cy = oc[3*i2+1], cz = oc[3*i2+2];
  float gx = (ax + bx + cx) / 3.0f;
  float gy = (ay + by + cy) / 3.0f;
  float gz = (az + bz + cz) / 3.0f;
  float w = gx*gx + gy*gy + gz*gz;
  fcurr[t] = make_float4(gx, gy, gz, w);

  float fx = -2.0f * gx, fy = -2.0f * gy, fz = -2.0f * gz;
  unsigned short fhx = bf16rn(fx), flx = bf16rn(fx - bf16tof(fhx));
  unsigned short fhy = bf16rn(fy), fly = bf16rn(fy - bf16tof(fhy));
  unsigned short fhz = bf16rn(fz), flz = bf16rn(fz - bf16tof(fhz));
  unsigned short whi = bf16rn(w),  wlo = bf16rn(w - bf16tof(whi));
  uint4 r0, r1;
  r0.x = (unsigned)fhx | ((unsigned)flx << 16);  // k0,k1
  r0.y = r0.x;                                    // k2,k3
  r0.z = (unsigned)fhy | ((unsigned)fly << 16);  // k4,k5
  r0.w = r0.z;                                    // k6,k7
  r1.x = (unsigned)fhz | ((unsigned)flz << 16);  // k8,k9
  r1.y = r1.x;                                    // k10,k11
  r1.z = (unsigned)whi | ((unsigned)wlo << 16);  // k12,k13
  r1.w = 0;                                       // k14,k15
  fpack[(size_t)t * 2 + 0] = r0;
  fpack[(size_t)t * 2 + 1] = r1;

  float nax = on[3*i0], nay = on[3*i0+1], naz = on[3*i0+2];
  float nbx = on[3*i1], nby = on[3*i1+1], nbz = on[3*i1+2];
  float ncx = on[3*i2], ncy = on[3*i2+1], ncz = on[3*i2+2];
  float hx = (nax + nbx + ncx) / 3.0f;
  float hy = (nay + nby + ncy) / 3.0f;
  float hz = (naz + nbz + ncz) / 3.0f;
  float e1x = nbx - nax, e1y = nby - nay, e1z = nbz - naz;
  float e2x = ncx - nax, e2y = ncy - nay, e2z = ncz - naz;
  float crx = e1y * e2z - e1z * e2y;
  float cry = e1z * e2x - e1x * e2z;
  float crz = e1x * e2y - e1y * e2x;
  float len = sqrtf(crx*crx + cry*cry + crz*crz);
  float inv = 1.0f / (len + 1e-12f);
  fnext[2 * (size_t)t + 0] = make_float4(hx, hy, hz, 0.0f);
  fnext[2 * (size_t)t + 1] = make_float4(crx*inv, cry*inv, crz*inv, 0.0f);
}

// ---------------------------------------------------------------------------
// Kernel B: 32x32x16 MFMA approximate-min pass, 2 B-frags per wave.
// Near MFMA-pipe floor (~6.8 us = 524288 MFMAs x 32 SIMD-cyc; min3 fold
// 4.5 us VALU hides underneath). Chunk-level (min, argmin-partition) kept
// in registers; ONE float2 store per vert per chunk (2 MB pchunk).
// LDS-staged A: 4 KB partition double-buffered via global_load_lds.
// Round 12: final-iteration barrier dropped (no LDS consumer after it).
// ---------------------------------------------------------------------------
__global__ __launch_bounds__(256, 4) void knn_mfma32(
    const float* __restrict__ cloth_curr,
    const uint4* __restrict__ fpack,     // 2 x uint4 per face (32 B)
    float2* __restrict__ pchunk) {       // [B][NCHUNK][N] (minval, part-idx)
  __shared__ uint4 abuf[2][256];   // 2 x 4 KB: one 128-face partition each

  int bid = blockIdx.x;            // [0, 1024)
  int s   = bid & 7;               // face chunk: [s*2048, (s+1)*2048)
  int vb  = (bid >> 3) & 63;       // 256-vert block
  int b   = bid >> 9;              // batch
  int lane = threadIdx.x & 63;
  int wid  = threadIdx.x >> 6;     // 0..3
  int h = lane >> 5;               // k-half
  int m = lane & 31;               // face-row / vert-col
  int vw = vb * 256 + wid * 64;    // wave's 64 verts

  // 2 B-frags: frag g covers verts vw + g*32 + m (col=lane&31, k=8*h+j)
  const short one = (short)0x3F80;
  bf16x8 bfrag0, bfrag1;
#pragma unroll
  for (int g = 0; g < 2; ++g) {
    const float* cp = cloth_curr + ((size_t)b * N_ + vw + g * 32 + m) * 3;
    float cxx = cp[0], cyy = cp[1], czz = cp[2];
    unsigned short chx = bf16rn(cxx), clx = bf16rn(cxx - bf16tof(chx));
    unsigned short chy = bf16rn(cyy), cly = bf16rn(cyy - bf16tof(chy));
    unsigned short chz = bf16rn(czz), clz = bf16rn(czz - bf16tof(chz));
    bf16x8 tq;
    if (h == 0) {
      tq[0] = (short)chx; tq[1] = (short)chx;
      tq[2] = (short)clx; tq[3] = (short)clx;
      tq[4] = (short)chy; tq[5] = (short)chy;
      tq[6] = (short)cly; tq[7] = (short)cly;
    } else {
      tq[0] = (short)chz; tq[1] = (short)chz;
      tq[2] = (short)clz; tq[3] = (short)clz;
      tq[4] = one; tq[5] = one;
      tq[6] = 0;   tq[7] = 0;
    }
    if (g == 0) bfrag0 = tq; else bfrag1 = tq;
  }

  f32x16 zc;
#pragma unroll
  for (int k = 0; k < 16; ++k) zc[k] = 0.0f;

  // chunk base (uint4 units): 2048 faces * 2 uint4. Partition = 256 uint4.
  const uint4* chunk = fpack + ((size_t)b * F_ + (size_t)s * 2048) * 2;

  // prologue: stage partition 0 into abuf[0] (each thread one 16B lane-slot)
  gload_lds16(chunk + wid * 64 + lane, &abuf[0][wid * 64]);
  __syncthreads();   // compiler drains vmcnt(0) before s_barrier

  // running chunk-level (min, argmin partition) per covered vert
  float rb0 = 3.4e38f, rb1 = 3.4e38f;
  int   rp0 = 0,       rp1 = 0;

  for (int part = 0; part < 16; ++part) {
    int cur = part & 1;
    // issue next partition's staging into the other buffer (no wait)
    if (part < 15)
      gload_lds16(chunk + (part + 1) * 256 + wid * 64 + lane,
                  &abuf[cur ^ 1][wid * 64]);

    float r0[8], r1[8];
#pragma unroll
    for (int k = 0; k < 8; ++k) { r0[k] = 3.4e38f; r1[k] = 3.4e38f; }

    // A-frag (face m of tile, half h) from LDS: idx (grp*64+m)*2+h and +32
    const uint4* lp = &abuf[cur][m * 2 + h];
#pragma unroll
    for (int grp = 0; grp < 2; ++grp) {   // 2 groups of 2 tiles
      uint4 a0 = lp[grp * 128];
      uint4 a1 = lp[grp * 128 + 64];
      bf16x8 av0 = __builtin_bit_cast(bf16x8, a0);
      bf16x8 av1 = __builtin_bit_cast(bf16x8, a1);
      f32x16 d00 = __builtin_amdgcn_mfma_f32_32x32x16_bf16(av0, bfrag0, zc, 0, 0, 0);
      f32x16 d01 = __builtin_amdgcn_mfma_f32_32x32x16_bf16(av0, bfrag1, zc, 0, 0, 0);
      f32x16 d10 = __builtin_amdgcn_mfma_f32_32x32x16_bf16(av1, bfrag0, zc, 0, 0, 0);
      f32x16 d11 = __builtin_amdgcn_mfma_f32_32x32x16_bf16(av1, bfrag1, zc, 0, 0, 0);
      // per-k running accumulators; min(min(a,b),c) fuses to v_min3_f32
#pragma unroll
      for (int k = 0; k < 8; ++k) {
        r0[k] = fminf(fminf(d00[k], d00[k + 8]), r0[k]);
        r0[k] = fminf(fminf(d10[k], d10[k + 8]), r0[k]);
        r1[k] = fminf(fminf(d01[k], d01[k + 8]), r1[k]);
        r1[k] = fminf(fminf(d11[k], d11[k + 8]), r1[k]);
      }
    }
    // fold 8 -> 1 per frag, merge halves
    float t0 = fminf(fminf(r0[0], r0[1]), r0[2]);
    t0 = fminf(fminf(t0, r0[3]), r0[4]);
    t0 = fminf(fminf(t0, r0[5]), r0[6]);
    float bmin0 = fminf(t0, r0[7]);
    float t1 = fminf(fminf(r1[0], r1[1]), r1[2]);
    t1 = fminf(fminf(t1, r1[3]), r1[4]);
    t1 = fminf(fminf(t1, r1[5]), r1[6]);
    float bmin1 = fminf(t1, r1[7]);
    bmin0 = fminf(bmin0, __shfl_xor(bmin0, 32, 64));
    bmin1 = fminf(bmin1, __shfl_xor(bmin1, 32, 64));

    // running argmin (strict <, ascending part => first-min-wins)
    bool u0 = bmin0 < rb0;
    rb0 = u0 ? bmin0 : rb0;
    rp0 = u0 ? part : rp0;
    bool u1 = bmin1 < rb1;
    rb1 = u1 ? bmin1 : rb1;
    rp1 = u1 ? part : rp1;

    // drain staging (vmcnt) + cross-wave LDS visibility for next partition
    if (part < 15) __syncthreads();
  }

  // one store per vert: (chunk-min, global partition index)
  float2* pout = pchunk + ((size_t)(b * NCHUNK_ + s)) * N_ + vw;
  if (lane < 32) {
    pout[lane]      = make_float2(rb0, __int_as_float(s * 16 + rp0));
    pout[32 + lane] = make_float2(rb1, __int_as_float(s * 16 + rp1));
  }
}

// ---------------------------------------------------------------------------
// Kernel C: epilogue, round 12: 8 threads (one octet) per (vertex, batch).
// 262144 threads = 4096 waves (was 512) -> the L2-latency-bound rescan
// gathers get 8x the TLP. Octet lane o scans chunk o (pass 1) and faces
// [o*16,(o+1)*16) of the winning partition (pass 2); shfl_xor butterflies
// merge with tie-break to LOWER chunk/face index == sequential
// first-min-wins semantics exactly. One atomic per block for the loss.
// ---------------------------------------------------------------------------
__global__ __launch_bounds__(256) void epilogue(
    const float* __restrict__ cloth_curr,
    const float* __restrict__ cloth_next,
    const float4* __restrict__ fcurr,
    const float4* __restrict__ fnext,
    const float2* __restrict__ pchunk,
    const int* __restrict__ iter_num,
    float* __restrict__ out) {
  int t = blockIdx.x * 256 + threadIdx.x;  // [0, 16*N)
  int o = t & 7;                           // octet lane
  int p = t >> 3;                          // (vertex, batch) pair [0, 2N)
  int i = p >> 1;                          // vertex
  int b = p & 1;                           // batch

  // weight ramp (double to match Python scalar math)
  int it = *iter_num;
  double itc = (double)(it - 50000);
  if (itc < 0.0) itc = 0.0;
  double prog = itc / 100000.0;
  if (prog > 1.0) prog = 1.0;
  float weight = (float)(1e-3 + (5e3 - 1e-3) * prog);
  float scale = weight * 0.5f;  // weight / B

  // pass 1: lane o reads chunk o's (min, part); butterfly-merge, tie->lower
  float2 v = pchunk[((size_t)(b * NCHUNK_ + o)) * N_ + i];
  float best = v.x;
  int bp = __float_as_int(v.y);
#pragma unroll
  for (int off = 1; off < 8; off <<= 1) {
    float ob = __shfl_xor(best, off, 64);
    int obp = __shfl_xor(bp, off, 64);
    bool take = (ob < best) || (ob == best && obp < bp);
    best = take ? ob : best;
    bp = take ? obp : bp;
  }

  // pass 2: exact fp32 rescan; lane o covers 16 of the 128 faces
  const float* cp = cloth_curr + ((size_t)b * N_ + i) * 3;
  float m2x = -2.0f * cp[0];
  float m2y = -2.0f * cp[1];
  float m2z = -2.0f * cp[2];
  const float4* fpp = fcurr + (size_t)b * F_ + (size_t)bp * TILE_ + o * 16;
  float sbest = 3.4e38f;
  int jwin = 0;
#pragma unroll 4
  for (int j = 0; j < 16; ++j) {
    float4 fc = fpp[j];
    float s = fmaf(m2x, fc.x, fmaf(m2y, fc.y, fmaf(m2z, fc.z, fc.w)));
    bool u = s < sbest;
    sbest = u ? s : sbest;
    jwin = u ? (o * 16 + j) : jwin;
  }
#pragma unroll
  for (int off = 1; off < 8; off <<= 1) {
    float os = __shfl_xor(sbest, off, 64);
    int oj = __shfl_xor(jwin, off, 64);
    bool take = (os < sbest) || (os == sbest && oj < jwin);
    sbest = take ? os : sbest;
    jwin = take ? oj : jwin;
  }
  int fidx = bp * TILE_ + jwin;

  float4 cent = fnext[2 * ((size_t)b * F_ + fidx) + 0];
  float4 nrm  = fnext[2 * ((size_t)b * F_ + fidx) + 1];
  const float* np2 = cloth_next + ((size_t)b * N_ + i) * 3;
  float dist = (np2[0] - cent.x) * nrm.x +
               (np2[1] - cent.y) * nrm.y +
               (np2[2] - cent.z) * nrm.z;
  float ip = fmaxf(1e-3f - dist, 0.0f);
  float acc = (o == 0) ? ip * ip * ip * scale : 0.0f;

  // combine the two batches: pairs p, p^1 sit 8 lanes apart (o=0 lanes)
  float pair = acc + __shfl_xor(acc, 8, 64);
  if (b == 0 && o == 0) out[1 + i] = pair;  // per_vert

  // block-level loss partial -> one atomic per block (acc==0 on o!=0)
  float r = acc;
#pragma unroll
  for (int off = 32; off > 0; off >>= 1) r += __shfl_down(r, off, 64);
  __shared__ float wsum[4];
  int lane = threadIdx.x & 63;
  int w = threadIdx.x >> 6;
  if (lane == 0) wsum[w] = r;
  __syncthreads();
  if (threadIdx.x == 0)
    atomicAdd(out, (wsum[0] + wsum[1]) + (wsum[2] + wsum[3]));
}

// ---------------------------------------------------------------------------
extern "C" void kernel_launch(void* const* d_in, const int* in_sizes, int n_in,
                              void* d_out, int out_size, void* d_ws, size_t ws_size,
                              hipStream_t stream) {
  const float* cloth_curr = (const float*)d_in[0];
  const float* cloth_next = (const float*)d_in[1];
  const float* obs_curr   = (const float*)d_in[2];
  const float* obs_next   = (const float*)d_in[3];
  const int*   faces      = (const int*)d_in[4];
  const int*   iter_num   = (const int*)d_in[5];
  float* out = (float*)d_out;

  // workspace: fcurr 512K @0 | fnext 1M @512K | fpack 1M @1.5M | pchunk 2M @3.5M
  char* w = (char*)d_ws;
  float4* fcurr = (float4*)(w);
  float4* fnext = (float4*)(w + 524288);
  uint4*  fpack = (uint4*)(w + 1572864);
  float2* pchunk = (float2*)(w + 3670016);

  face_precomp<<<(B_ * F_ + 127) / 128, 128, 0, stream>>>(
      obs_curr, obs_next, faces, fcurr, fnext, fpack, out);

  knn_mfma32<<<1024, 256, 0, stream>>>(cloth_curr, fpack, pchunk);

  epilogue<<<(16 * N_) / 256, 256, 0, stream>>>(
      cloth_curr, cloth_next, fcurr, fnext, pchunk, iter_num, out);
}

// Round 4
// 108.894 us; speedup vs baseline: 1.0132x; 1.0132x over previous
//
#include <hip/hip_runtime.h>
#include <math.h>

// Problem constants (fixed shapes from reference)
#define B_ 2
#define N_ 16384
#define M_ 12000
#define F_ 16384

#define P_ 128          // face partitions (argmin granularity)
#define TILE_ 128       // faces per partition
#define NCHUNK_ 8       // face chunks (knn blocks per vert-block)

typedef short bf16x8 __attribute__((ext_vector_type(8)));
typedef float f32x16 __attribute__((ext_vector_type(16)));

__device__ __host__ inline unsigned short bf16rn(float x) {
  unsigned int u = __float_as_uint(x);
  u = (u + 0x7FFFu + ((u >> 16) & 1u)) >> 16;
  return (unsigned short)u;
}
__device__ inline float bf16tof(unsigned short h) {
  return __uint_as_float(((unsigned int)h) << 16);
}

// async global->LDS, 16B per lane. LDS dest must be wave-uniform base;
// HW writes base + lane*16 (linear). Global src is per-lane.
__device__ __forceinline__ void gload_lds16(const uint4* g, uint4* l) {
  __builtin_amdgcn_global_load_lds(
      (const __attribute__((address_space(1))) void*)g,
      (__attribute__((address_space(3))) void*)l, 16, 0, 0);
}

// ---------------------------------------------------------------------------
// Kernel A: per-face precompute + out[0] zero-init. (R2-verified form:
// 256-thread blocks; octet/128-thread variants regressed in R3.)
//   fcurr[f] = (centroid_curr.xyz, |centroid_curr|^2)   (exact fp32 chain)
//   fnext[2f] = centroid_next, fnext[2f+1] = unit normal
//   fpack[f]  = 16 bf16 (32B): K=16 A-operand for mfma_32x32x16:
//     k0-3 {fhx,flx,fhx,flx} k4-7 {y} k8-11 {z} k12,13 {whi,wlo} k14,15 0
// ---------------------------------------------------------------------------
__global__ __launch_bounds__(256) void face_precomp(
    const float* __restrict__ obs_curr,
    const float* __restrict__ obs_next,
    const int* __restrict__ faces,
    float4* __restrict__ fcurr,
    float4* __restrict__ fnext,
    uint4* __restrict__ fpack,
    float* __restrict__ out) {
  int t = blockIdx.x * 256 + threadIdx.x;
  if (t == 0) out[0] = 0.0f;  // epilogue (later, same stream) accumulates
  if (t >= B_ * F_) return;
  int b = t / F_;
  const float* oc = obs_curr + (size_t)b * M_ * 3;
  const float* on = obs_next + (size_t)b * M_ * 3;
  int i0 = faces[3 * (size_t)t + 0];
  int i1 = faces[3 * (size_t)t + 1];
  int i2 = faces[3 * (size_t)t + 2];

  float ax = oc[3*i0], ay = oc[3*i0+1], az = oc[3*i0+2];
  float bx = oc[3*i1], by = oc[3*i1+1], bz = oc[3*i1+2];
  float cx = oc[3*i2], cy = oc[3*i2+1], cz = oc[3*i2+2];
  float gx = (ax + bx + cx) / 3.0f;
  float gy = (ay + by + cy) / 3.0f;
  float gz = (az + bz + cz) / 3.0f;
  float w = gx*gx + gy*gy + gz*gz;
  fcurr[t] = make_float4(gx, gy, gz, w);

  float fx = -2.0f * gx, fy = -2.0f * gy, fz = -2.0f * gz;
  unsigned short fhx = bf16rn(fx), flx = bf16rn(fx - bf16tof(fhx));
  unsigned short fhy = bf16rn(fy), fly = bf16rn(fy - bf16tof(fhy));
  unsigned short fhz = bf16rn(fz), flz = bf16rn(fz - bf16tof(fhz));
  unsigned short whi = bf16rn(w),  wlo = bf16rn(w - bf16tof(whi));
  uint4 r0, r1;
  r0.x = (unsigned)fhx | ((unsigned)flx << 16);  // k0,k1
  r0.y = r0.x;                                    // k2,k3
  r0.z = (unsigned)fhy | ((unsigned)fly << 16);  // k4,k5
  r0.w = r0.z;                                    // k6,k7
  r1.x = (unsigned)fhz | ((unsigned)flz << 16);  // k8,k9
  r1.y = r1.x;                                    // k10,k11
  r1.z = (unsigned)whi | ((unsigned)wlo << 16);  // k12,k13
  r1.w = 0;                                       // k14,k15
  fpack[(size_t)t * 2 + 0] = r0;
  fpack[(size_t)t * 2 + 1] = r1;

  float nax = on[3*i0], nay = on[3*i0+1], naz = on[3*i0+2];
  float nbx = on[3*i1], nby = on[3*i1+1], nbz = on[3*i1+2];
  float ncx = on[3*i2], ncy = on[3*i2+1], ncz = on[3*i2+2];
  float hx = (nax + nbx + ncx) / 3.0f;
  float hy = (nay + nby + ncy) / 3.0f;
  float hz = (naz + nbz + ncz) / 3.0f;
  float e1x = nbx - nax, e1y = nby - nay, e1z = nbz - naz;
  float e2x = ncx - nax, e2y = ncy - nay, e2z = ncz - naz;
  float crx = e1y * e2z - e1z * e2y;
  float cry = e1z * e2x - e1x * e2z;
  float crz = e1x * e2y - e1y * e2x;
  float len = sqrtf(crx*crx + cry*cry + crz*crz);
  float inv = 1.0f / (len + 1e-12f);
  fnext[2 * (size_t)t + 0] = make_float4(hx, hy, hz, 0.0f);
  fnext[2 * (size_t)t + 1] = make_float4(crx*inv, cry*inv, crz*inv, 0.0f);
}

// ---------------------------------------------------------------------------
// Kernel B: 32x32x16 MFMA approximate-min pass, 2 B-frags per wave.
// VALU-bound (~4.8 us: 64 min3/partition/lane + fold/argmin; MFMA pipe
// only ~1.7 us, hides underneath). min3 count is minimal (2 new D-values
// per min3). Round 13: stage TWO partitions per LDS buffer (8 KB x 2,
// 64 KB/block at 4 blocks/CU) -> barriers halved 16 -> 8. Per-partition
// (min, argmin) semantics bit-identical. One float2 store per vert/chunk.
// ---------------------------------------------------------------------------
__global__ __launch_bounds__(256, 4) void knn_mfma32(
    const float* __restrict__ cloth_curr,
    const uint4* __restrict__ fpack,     // 2 x uint4 per face (32 B)
    float2* __restrict__ pchunk) {       // [B][NCHUNK][N] (minval, part-idx)
  __shared__ uint4 abuf[2][512];   // 2 x 8 KB: two 128-face partitions each

  int bid = blockIdx.x;            // [0, 1024)
  int s   = bid & 7;               // face chunk: [s*2048, (s+1)*2048)
  int vb  = (bid >> 3) & 63;       // 256-vert block
  int b   = bid >> 9;              // batch
  int lane = threadIdx.x & 63;
  int wid  = threadIdx.x >> 6;     // 0..3
  int h = lane >> 5;               // k-half
  int m = lane & 31;               // face-row / vert-col
  int vw = vb * 256 + wid * 64;    // wave's 64 verts

  // 2 B-frags: frag g covers verts vw + g*32 + m (col=lane&31, k=8*h+j)
  const short one = (short)0x3F80;
  bf16x8 bfrag0, bfrag1;
#pragma unroll
  for (int g = 0; g < 2; ++g) {
    const float* cp = cloth_curr + ((size_t)b * N_ + vw + g * 32 + m) * 3;
    float cxx = cp[0], cyy = cp[1], czz = cp[2];
    unsigned short chx = bf16rn(cxx), clx = bf16rn(cxx - bf16tof(chx));
    unsigned short chy = bf16rn(cyy), cly = bf16rn(cyy - bf16tof(chy));
    unsigned short chz = bf16rn(czz), clz = bf16rn(czz - bf16tof(chz));
    bf16x8 tq;
    if (h == 0) {
      tq[0] = (short)chx; tq[1] = (short)chx;
      tq[2] = (short)clx; tq[3] = (short)clx;
      tq[4] = (short)chy; tq[5] = (short)chy;
      tq[6] = (short)cly; tq[7] = (short)cly;
    } else {
      tq[0] = (short)chz; tq[1] = (short)chz;
      tq[2] = (short)clz; tq[3] = (short)clz;
      tq[4] = one; tq[5] = one;
      tq[6] = 0;   tq[7] = 0;
    }
    if (g == 0) bfrag0 = tq; else bfrag1 = tq;
  }

  f32x16 zc;
#pragma unroll
  for (int k = 0; k < 16; ++k) zc[k] = 0.0f;

  // chunk base (uint4 units): 2048 faces * 2 uint4. Partition = 256 uint4,
  // partition-pair = 512 uint4.
  const uint4* chunk = fpack + ((size_t)b * F_ + (size_t)s * 2048) * 2;

  // prologue: stage partition pair 0 (parts 0,1) into abuf[0]
  gload_lds16(chunk + wid * 64 + lane, &abuf[0][wid * 64]);
  gload_lds16(chunk + 256 + wid * 64 + lane, &abuf[0][256 + wid * 64]);
  __syncthreads();   // compiler drains vmcnt(0) before s_barrier

  // running chunk-level (min, argmin partition) per covered vert
  float rb0 = 3.4e38f, rb1 = 3.4e38f;
  int   rp0 = 0,       rp1 = 0;

  for (int pp = 0; pp < 8; ++pp) {
    int cur = pp & 1;
    // issue next pair's staging into the other buffer (no wait)
    if (pp < 7) {
      gload_lds16(chunk + (pp + 1) * 512 + wid * 64 + lane,
                  &abuf[cur ^ 1][wid * 64]);
      gload_lds16(chunk + (pp + 1) * 512 + 256 + wid * 64 + lane,
                  &abuf[cur ^ 1][256 + wid * 64]);
    }

#pragma unroll
    for (int sub = 0; sub < 2; ++sub) {
      int part = pp * 2 + sub;
      float r0[8], r1[8];
#pragma unroll
      for (int k = 0; k < 8; ++k) { r0[k] = 3.4e38f; r1[k] = 3.4e38f; }

      // A-frag (face m of tile, half h) from LDS
      const uint4* lp = &abuf[cur][sub * 256 + m * 2 + h];
#pragma unroll
      for (int grp = 0; grp < 2; ++grp) {   // 2 groups of 2 tiles
        uint4 a0 = lp[grp * 128];
        uint4 a1 = lp[grp * 128 + 64];
        bf16x8 av0 = __builtin_bit_cast(bf16x8, a0);
        bf16x8 av1 = __builtin_bit_cast(bf16x8, a1);
        f32x16 d00 = __builtin_amdgcn_mfma_f32_32x32x16_bf16(av0, bfrag0, zc, 0, 0, 0);
        f32x16 d01 = __builtin_amdgcn_mfma_f32_32x32x16_bf16(av0, bfrag1, zc, 0, 0, 0);
        f32x16 d10 = __builtin_amdgcn_mfma_f32_32x32x16_bf16(av1, bfrag0, zc, 0, 0, 0);
        f32x16 d11 = __builtin_amdgcn_mfma_f32_32x32x16_bf16(av1, bfrag1, zc, 0, 0, 0);
        // per-k running accumulators; min(min(a,b),c) fuses to v_min3_f32
#pragma unroll
        for (int k = 0; k < 8; ++k) {
          r0[k] = fminf(fminf(d00[k], d00[k + 8]), r0[k]);
          r0[k] = fminf(fminf(d10[k], d10[k + 8]), r0[k]);
          r1[k] = fminf(fminf(d01[k], d01[k + 8]), r1[k]);
          r1[k] = fminf(fminf(d11[k], d11[k + 8]), r1[k]);
        }
      }
      // fold 8 -> 1 per frag, merge halves
      float t0 = fminf(fminf(r0[0], r0[1]), r0[2]);
      t0 = fminf(fminf(t0, r0[3]), r0[4]);
      t0 = fminf(fminf(t0, r0[5]), r0[6]);
      float bmin0 = fminf(t0, r0[7]);
      float t1 = fminf(fminf(r1[0], r1[1]), r1[2]);
      t1 = fminf(fminf(t1, r1[3]), r1[4]);
      t1 = fminf(fminf(t1, r1[5]), r1[6]);
      float bmin1 = fminf(t1, r1[7]);
      bmin0 = fminf(bmin0, __shfl_xor(bmin0, 32, 64));
      bmin1 = fminf(bmin1, __shfl_xor(bmin1, 32, 64));

      // running argmin (strict <, ascending part => first-min-wins)
      bool u0 = bmin0 < rb0;
      rb0 = u0 ? bmin0 : rb0;
      rp0 = u0 ? part : rp0;
      bool u1 = bmin1 < rb1;
      rb1 = u1 ? bmin1 : rb1;
      rp1 = u1 ? part : rp1;
    }

    // drain staging (vmcnt) + cross-wave LDS visibility for next pair
    if (pp < 7) __syncthreads();
  }

  // one store per vert: (chunk-min, global partition index)
  float2* pout = pchunk + ((size_t)(b * NCHUNK_ + s)) * N_ + vw;
  if (lane < 32) {
    pout[lane]      = make_float2(rb0, __int_as_float(s * 16 + rp0));
    pout[32 + lane] = make_float2(rb1, __int_as_float(s * 16 + rp1));
  }
}

// ---------------------------------------------------------------------------
// Kernel C: per-(vertex,batch)-thread epilogue (R2-verified form; the
// octet split regressed in R3 — redundant loads + de-coalesced pass 1).
// Pass 1: 8 float2 chunk-minima. Pass 2: exact fp32 rescan of winning
// 128-face partition; plane distance + interpenetration; one atomic/block.
// ---------------------------------------------------------------------------
__global__ __launch_bounds__(256) void epilogue(
    const float* __restrict__ cloth_curr,
    const float* __restrict__ cloth_next,
    const float4* __restrict__ fcurr,
    const float4* __restrict__ fnext,
    const float2* __restrict__ pchunk,
    const int* __restrict__ iter_num,
    float* __restrict__ out) {
  int t = blockIdx.x * 256 + threadIdx.x;  // [0, 2*N)
  int i = t >> 1;                          // vertex
  int b = t & 1;                           // batch

  // weight ramp (double to match Python scalar math)
  int it = *iter_num;
  double itc = (double)(it - 50000);
  if (itc < 0.0) itc = 0.0;
  double prog = itc / 100000.0;
  if (prog > 1.0) prog = 1.0;
  float weight = (float)(1e-3 + (5e3 - 1e-3) * prog);
  float scale = weight * 0.5f;  // weight / B

  // pass 1: argmin partition over chunk minima (8 float2 loads)
  float best = 3.4e38f;
  int bp = 0;
#pragma unroll
  for (int c = 0; c < NCHUNK_; ++c) {
    float2 v = pchunk[((size_t)(b * NCHUNK_ + c)) * N_ + i];
    bool mm = v.x < best;
    best = mm ? v.x : best;
    bp = mm ? __float_as_int(v.y) : bp;
  }

  // pass 2: exact fp32 rescan of winning partition
  const float* cp = cloth_curr + ((size_t)b * N_ + i) * 3;
  float m2x = -2.0f * cp[0];
  float m2y = -2.0f * cp[1];
  float m2z = -2.0f * cp[2];
  const float4* fpp = fcurr + (size_t)b * F_ + (size_t)bp * TILE_;
  float sbest = 3.4e38f;
  int jwin = 0;
#pragma unroll 4
  for (int j = 0; j < TILE_; ++j) {
    float4 fc = fpp[j];
    float s = fmaf(m2x, fc.x, fmaf(m2y, fc.y, fmaf(m2z, fc.z, fc.w)));
    bool u = s < sbest;
    sbest = u ? s : sbest;
    jwin = u ? j : jwin;
  }
  int fidx = bp * TILE_ + jwin;

  float4 cent = fnext[2 * ((size_t)b * F_ + fidx) + 0];
  float4 nrm  = fnext[2 * ((size_t)b * F_ + fidx) + 1];
  const float* np2 = cloth_next + ((size_t)b * N_ + i) * 3;
  float dist = (np2[0] - cent.x) * nrm.x +
               (np2[1] - cent.y) * nrm.y +
               (np2[2] - cent.z) * nrm.z;
  float ip = fmaxf(1e-3f - dist, 0.0f);
  float acc = ip * ip * ip * scale;

  // combine the two batches (lanes 2k / 2k+1 hold b=0 / b=1 of vertex i)
  float pair = acc + __shfl_xor(acc, 1, 64);
  if (b == 0) out[1 + i] = pair;  // per_vert

  // block-level loss partial -> one atomic per block
  float r = acc;
#pragma unroll
  for (int off = 32; off > 0; off >>= 1) r += __shfl_down(r, off, 64);
  __shared__ float wsum[4];
  int lane = threadIdx.x & 63;
  int w = threadIdx.x >> 6;
  if (lane == 0) wsum[w] = r;
  __syncthreads();
  if (threadIdx.x == 0)
    atomicAdd(out, (wsum[0] + wsum[1]) + (wsum[2] + wsum[3]));
}

// ---------------------------------------------------------------------------
extern "C" void kernel_launch(void* const* d_in, const int* in_sizes, int n_in,
                              void* d_out, int out_size, void* d_ws, size_t ws_size,
                              hipStream_t stream) {
  const float* cloth_curr = (const float*)d_in[0];
  const float* cloth_next = (const float*)d_in[1];
  const float* obs_curr   = (const float*)d_in[2];
  const float* obs_next   = (const float*)d_in[3];
  const int*   faces      = (const int*)d_in[4];
  const int*   iter_num   = (const int*)d_in[5];
  float* out = (float*)d_out;

  // workspace: fcurr 512K @0 | fnext 1M @512K | fpack 1M @1.5M | pchunk 2M @3.5M
  char* w = (char*)d_ws;
  float4* fcurr = (float4*)(w);
  float4* fnext = (float4*)(w + 524288);
  uint4*  fpack = (uint4*)(w + 1572864);
  float2* pchunk = (float2*)(w + 3670016);

  face_precomp<<<(B_ * F_ + 255) / 256, 256, 0, stream>>>(
      obs_curr, obs_next, faces, fcurr, fnext, fpack, out);

  knn_mfma32<<<1024, 256, 0, stream>>>(cloth_curr, fpack, pchunk);

  epilogue<<<(2 * N_) / 256, 256, 0, stream>>>(
      cloth_curr, cloth_next, fcurr, fnext, pchunk, iter_num, out);
}

// Round 5
// 105.948 us; speedup vs baseline: 1.0414x; 1.0278x over previous
//
#include <hip/hip_runtime.h>
#include <math.h>

// Problem constants (fixed shapes from reference)
#define B_ 2
#define N_ 16384
#define M_ 12000
#define F_ 16384

#define P_ 128          // face partitions (argmin granularity)
#define TILE_ 128       // faces per partition
#define NCHUNK_ 8       // face chunks (knn blocks per vert-block)

typedef short bf16x8 __attribute__((ext_vector_type(8)));
typedef float f32x16 __attribute__((ext_vector_type(16)));

__device__ __host__ inline unsigned short bf16rn(float x) {
  unsigned int u = __float_as_uint(x);
  u = (u + 0x7FFFu + ((u >> 16) & 1u)) >> 16;
  return (unsigned short)u;
}
__device__ inline float bf16tof(unsigned short h) {
  return __uint_as_float(((unsigned int)h) << 16);
}

// async global->LDS, 16B per lane. LDS dest must be wave-uniform base;
// HW writes base + lane*16 (linear). Global src is per-lane.
__device__ __forceinline__ void gload_lds16(const uint4* g, uint4* l) {
  __builtin_amdgcn_global_load_lds(
      (const __attribute__((address_space(1))) void*)g,
      (__attribute__((address_space(3))) void*)l, 16, 0, 0);
}

// ---------------------------------------------------------------------------
// Kernel A: per-face precompute + out[0] zero-init.
// Round 14: pure grid reshape 128x256 -> 256x128 (same per-thread work &
// memory pattern; latency-bound gather now spreads over all 256 CUs).
//   fcurr[f] = (centroid_curr.xyz, |centroid_curr|^2)   (exact fp32 chain)
//   fnext[2f] = centroid_next, fnext[2f+1] = unit normal
//   fpack[f]  = 16 bf16 (32B): K=16 A-operand for mfma_32x32x16:
//     k0-3 {fhx,flx,fhx,flx} k4-7 {y} k8-11 {z} k12,13 {whi,wlo} k14,15 0
// ---------------------------------------------------------------------------
__global__ __launch_bounds__(128) void face_precomp(
    const float* __restrict__ obs_curr,
    const float* __restrict__ obs_next,
    const int* __restrict__ faces,
    float4* __restrict__ fcurr,
    float4* __restrict__ fnext,
    uint4* __restrict__ fpack,
    float* __restrict__ out) {
  int t = blockIdx.x * 128 + threadIdx.x;
  if (t == 0) out[0] = 0.0f;  // epilogue (later, same stream) accumulates
  if (t >= B_ * F_) return;
  int b = t / F_;
  const float* oc = obs_curr + (size_t)b * M_ * 3;
  const float* on = obs_next + (size_t)b * M_ * 3;
  int i0 = faces[3 * (size_t)t + 0];
  int i1 = faces[3 * (size_t)t + 1];
  int i2 = faces[3 * (size_t)t + 2];

  float ax = oc[3*i0], ay = oc[3*i0+1], az = oc[3*i0+2];
  float bx = oc[3*i1], by = oc[3*i1+1], bz = oc[3*i1+2];
  float cx = oc[3*i2], cy = oc[3*i2+1], cz = oc[3*i2+2];
  float gx = (ax + bx + cx) / 3.0f;
  float gy = (ay + by + cy) / 3.0f;
  float gz = (az + bz + cz) / 3.0f;
  float w = gx*gx + gy*gy + gz*gz;
  fcurr[t] = make_float4(gx, gy, gz, w);

  float fx = -2.0f * gx, fy = -2.0f * gy, fz = -2.0f * gz;
  unsigned short fhx = bf16rn(fx), flx = bf16rn(fx - bf16tof(fhx));
  unsigned short fhy = bf16rn(fy), fly = bf16rn(fy - bf16tof(fhy));
  unsigned short fhz = bf16rn(fz), flz = bf16rn(fz - bf16tof(fhz));
  unsigned short whi = bf16rn(w),  wlo = bf16rn(w - bf16tof(whi));
  uint4 r0, r1;
  r0.x = (unsigned)fhx | ((unsigned)flx << 16);  // k0,k1
  r0.y = r0.x;                                    // k2,k3
  r0.z = (unsigned)fhy | ((unsigned)fly << 16);  // k4,k5
  r0.w = r0.z;                                    // k6,k7
  r1.x = (unsigned)fhz | ((unsigned)flz << 16);  // k8,k9
  r1.y = r1.x;                                    // k10,k11
  r1.z = (unsigned)whi | ((unsigned)wlo << 16);  // k12,k13
  r1.w = 0;                                       // k14,k15
  fpack[(size_t)t * 2 + 0] = r0;
  fpack[(size_t)t * 2 + 1] = r1;

  float nax = on[3*i0], nay = on[3*i0+1], naz = on[3*i0+2];
  float nbx = on[3*i1], nby = on[3*i1+1], nbz = on[3*i1+2];
  float ncx = on[3*i2], ncy = on[3*i2+1], ncz = on[3*i2+2];
  float hx = (nax + nbx + ncx) / 3.0f;
  float hy = (nay + nby + ncy) / 3.0f;
  float hz = (naz + nbz + ncz) / 3.0f;
  float e1x = nbx - nax, e1y = nby - nay, e1z = nbz - naz;
  float e2x = ncx - nax, e2y = ncy - nay, e2z = ncz - naz;
  float crx = e1y * e2z - e1z * e2y;
  float cry = e1z * e2x - e1x * e2z;
  float crz = e1x * e2y - e1y * e2x;
  float len = sqrtf(crx*crx + cry*cry + crz*crz);
  float inv = 1.0f / (len + 1e-12f);
  fnext[2 * (size_t)t + 0] = make_float4(hx, hy, hz, 0.0f);
  fnext[2 * (size_t)t + 1] = make_float4(crx*inv, cry*inv, crz*inv, 0.0f);
}

// ---------------------------------------------------------------------------
// Kernel B: 32x32x16 MFMA approximate-min pass (R2-verified form — best of
// R10/R13 variants; pair-staging regressed in R4, leave this kernel alone).
// VALU-bound ~4.5 us vs ~3.4 us min3 floor; MFMA 1.7 us hides under it.
// Chunk-level (min, argmin-partition) in registers; ONE float2 store per
// vert per chunk. LDS 4 KB partition double-buffered via global_load_lds.
// ---------------------------------------------------------------------------
__global__ __launch_bounds__(256, 4) void knn_mfma32(
    const float* __restrict__ cloth_curr,
    const uint4* __restrict__ fpack,     // 2 x uint4 per face (32 B)
    float2* __restrict__ pchunk) {       // [B][NCHUNK][N] (minval, part-idx)
  __shared__ uint4 abuf[2][256];   // 2 x 4 KB: one 128-face partition each

  int bid = blockIdx.x;            // [0, 1024)
  int s   = bid & 7;               // face chunk: [s*2048, (s+1)*2048)
  int vb  = (bid >> 3) & 63;       // 256-vert block
  int b   = bid >> 9;              // batch
  int lane = threadIdx.x & 63;
  int wid  = threadIdx.x >> 6;     // 0..3
  int h = lane >> 5;               // k-half
  int m = lane & 31;               // face-row / vert-col
  int vw = vb * 256 + wid * 64;    // wave's 64 verts

  // 2 B-frags: frag g covers verts vw + g*32 + m (col=lane&31, k=8*h+j)
  const short one = (short)0x3F80;
  bf16x8 bfrag0, bfrag1;
#pragma unroll
  for (int g = 0; g < 2; ++g) {
    const float* cp = cloth_curr + ((size_t)b * N_ + vw + g * 32 + m) * 3;
    float cxx = cp[0], cyy = cp[1], czz = cp[2];
    unsigned short chx = bf16rn(cxx), clx = bf16rn(cxx - bf16tof(chx));
    unsigned short chy = bf16rn(cyy), cly = bf16rn(cyy - bf16tof(chy));
    unsigned short chz = bf16rn(czz), clz = bf16rn(czz - bf16tof(chz));
    bf16x8 tq;
    if (h == 0) {
      tq[0] = (short)chx; tq[1] = (short)chx;
      tq[2] = (short)clx; tq[3] = (short)clx;
      tq[4] = (short)chy; tq[5] = (short)chy;
      tq[6] = (short)cly; tq[7] = (short)cly;
    } else {
      tq[0] = (short)chz; tq[1] = (short)chz;
      tq[2] = (short)clz; tq[3] = (short)clz;
      tq[4] = one; tq[5] = one;
      tq[6] = 0;   tq[7] = 0;
    }
    if (g == 0) bfrag0 = tq; else bfrag1 = tq;
  }

  f32x16 zc;
#pragma unroll
  for (int k = 0; k < 16; ++k) zc[k] = 0.0f;

  // chunk base (uint4 units): 2048 faces * 2 uint4. Partition = 256 uint4.
  const uint4* chunk = fpack + ((size_t)b * F_ + (size_t)s * 2048) * 2;

  // prologue: stage partition 0 into abuf[0] (each thread one 16B lane-slot)
  gload_lds16(chunk + wid * 64 + lane, &abuf[0][wid * 64]);
  __syncthreads();   // compiler drains vmcnt(0) before s_barrier

  // running chunk-level (min, argmin partition) per covered vert
  float rb0 = 3.4e38f, rb1 = 3.4e38f;
  int   rp0 = 0,       rp1 = 0;

  for (int part = 0; part < 16; ++part) {
    int cur = part & 1;
    // issue next partition's staging into the other buffer (no wait)
    if (part < 15)
      gload_lds16(chunk + (part + 1) * 256 + wid * 64 + lane,
                  &abuf[cur ^ 1][wid * 64]);

    float r0[8], r1[8];
#pragma unroll
    for (int k = 0; k < 8; ++k) { r0[k] = 3.4e38f; r1[k] = 3.4e38f; }

    // A-frag (face m of tile, half h) from LDS: idx (grp*64+m)*2+h and +32
    const uint4* lp = &abuf[cur][m * 2 + h];
#pragma unroll
    for (int grp = 0; grp < 2; ++grp) {   // 2 groups of 2 tiles
      uint4 a0 = lp[grp * 128];
      uint4 a1 = lp[grp * 128 + 64];
      bf16x8 av0 = __builtin_bit_cast(bf16x8, a0);
      bf16x8 av1 = __builtin_bit_cast(bf16x8, a1);
      f32x16 d00 = __builtin_amdgcn_mfma_f32_32x32x16_bf16(av0, bfrag0, zc, 0, 0, 0);
      f32x16 d01 = __builtin_amdgcn_mfma_f32_32x32x16_bf16(av0, bfrag1, zc, 0, 0, 0);
      f32x16 d10 = __builtin_amdgcn_mfma_f32_32x32x16_bf16(av1, bfrag0, zc, 0, 0, 0);
      f32x16 d11 = __builtin_amdgcn_mfma_f32_32x32x16_bf16(av1, bfrag1, zc, 0, 0, 0);
      // per-k running accumulators; min(min(a,b),c) fuses to v_min3_f32
#pragma unroll
      for (int k = 0; k < 8; ++k) {
        r0[k] = fminf(fminf(d00[k], d00[k + 8]), r0[k]);
        r0[k] = fminf(fminf(d10[k], d10[k + 8]), r0[k]);
        r1[k] = fminf(fminf(d01[k], d01[k + 8]), r1[k]);
        r1[k] = fminf(fminf(d11[k], d11[k + 8]), r1[k]);
      }
    }
    // fold 8 -> 1 per frag, merge halves
    float t0 = fminf(fminf(r0[0], r0[1]), r0[2]);
    t0 = fminf(fminf(t0, r0[3]), r0[4]);
    t0 = fminf(fminf(t0, r0[5]), r0[6]);
    float bmin0 = fminf(t0, r0[7]);
    float t1 = fminf(fminf(r1[0], r1[1]), r1[2]);
    t1 = fminf(fminf(t1, r1[3]), r1[4]);
    t1 = fminf(fminf(t1, r1[5]), r1[6]);
    float bmin1 = fminf(t1, r1[7]);
    bmin0 = fminf(bmin0, __shfl_xor(bmin0, 32, 64));
    bmin1 = fminf(bmin1, __shfl_xor(bmin1, 32, 64));

    // running argmin (strict <, ascending part => first-min-wins)
    bool u0 = bmin0 < rb0;
    rb0 = u0 ? bmin0 : rb0;
    rp0 = u0 ? part : rp0;
    bool u1 = bmin1 < rb1;
    rb1 = u1 ? bmin1 : rb1;
    rp1 = u1 ? part : rp1;

    // drain staging (vmcnt) + cross-wave LDS visibility for next partition
    if (part < 15) __syncthreads();
  }

  // one store per vert: (chunk-min, global partition index)
  float2* pout = pchunk + ((size_t)(b * NCHUNK_ + s)) * N_ + vw;
  if (lane < 32) {
    pout[lane]      = make_float2(rb0, __int_as_float(s * 16 + rp0));
    pout[32 + lane] = make_float2(rb1, __int_as_float(s * 16 + rp1));
  }
}

// ---------------------------------------------------------------------------
// Kernel C: per-(vertex,batch)-thread epilogue (R2-verified logic).
// Round 14: pure grid reshape 128x256 -> 256x128. Same 1:1 thread->(v,b)
// mapping, same per-thread loads and coalescing; latency-bound rescan now
// covers all 256 CUs instead of 128. wsum shrinks to 2 waves.
// ---------------------------------------------------------------------------
__global__ __launch_bounds__(128) void epilogue(
    const float* __restrict__ cloth_curr,
    const float* __restrict__ cloth_next,
    const float4* __restrict__ fcurr,
    const float4* __restrict__ fnext,
    const float2* __restrict__ pchunk,
    const int* __restrict__ iter_num,
    float* __restrict__ out) {
  int t = blockIdx.x * 128 + threadIdx.x;  // [0, 2*N)
  int i = t >> 1;                          // vertex
  int b = t & 1;                           // batch

  // weight ramp (double to match Python scalar math)
  int it = *iter_num;
  double itc = (double)(it - 50000);
  if (itc < 0.0) itc = 0.0;
  double prog = itc / 100000.0;
  if (prog > 1.0) prog = 1.0;
  float weight = (float)(1e-3 + (5e3 - 1e-3) * prog);
  float scale = weight * 0.5f;  // weight / B

  // pass 1: argmin partition over chunk minima (8 float2 loads)
  float best = 3.4e38f;
  int bp = 0;
#pragma unroll
  for (int c = 0; c < NCHUNK_; ++c) {
    float2 v = pchunk[((size_t)(b * NCHUNK_ + c)) * N_ + i];
    bool mm = v.x < best;
    best = mm ? v.x : best;
    bp = mm ? __float_as_int(v.y) : bp;
  }

  // pass 2: exact fp32 rescan of winning partition
  const float* cp = cloth_curr + ((size_t)b * N_ + i) * 3;
  float m2x = -2.0f * cp[0];
  float m2y = -2.0f * cp[1];
  float m2z = -2.0f * cp[2];
  const float4* fpp = fcurr + (size_t)b * F_ + (size_t)bp * TILE_;
  float sbest = 3.4e38f;
  int jwin = 0;
#pragma unroll 4
  for (int j = 0; j < TILE_; ++j) {
    float4 fc = fpp[j];
    float s = fmaf(m2x, fc.x, fmaf(m2y, fc.y, fmaf(m2z, fc.z, fc.w)));
    bool u = s < sbest;
    sbest = u ? s : sbest;
    jwin = u ? j : jwin;
  }
  int fidx = bp * TILE_ + jwin;

  float4 cent = fnext[2 * ((size_t)b * F_ + fidx) + 0];
  float4 nrm  = fnext[2 * ((size_t)b * F_ + fidx) + 1];
  const float* np2 = cloth_next + ((size_t)b * N_ + i) * 3;
  float dist = (np2[0] - cent.x) * nrm.x +
               (np2[1] - cent.y) * nrm.y +
               (np2[2] - cent.z) * nrm.z;
  float ip = fmaxf(1e-3f - dist, 0.0f);
  float acc = ip * ip * ip * scale;

  // combine the two batches (lanes 2k / 2k+1 hold b=0 / b=1 of vertex i)
  float pair = acc + __shfl_xor(acc, 1, 64);
  if (b == 0) out[1 + i] = pair;  // per_vert

  // block-level loss partial -> one atomic per block (2 waves)
  float r = acc;
#pragma unroll
  for (int off = 32; off > 0; off >>= 1) r += __shfl_down(r, off, 64);
  __shared__ float wsum[2];
  int lane = threadIdx.x & 63;
  int w = threadIdx.x >> 6;
  if (lane == 0) wsum[w] = r;
  __syncthreads();
  if (threadIdx.x == 0)
    atomicAdd(out, wsum[0] + wsum[1]);
}

// ---------------------------------------------------------------------------
extern "C" void kernel_launch(void* const* d_in, const int* in_sizes, int n_in,
                              void* d_out, int out_size, void* d_ws, size_t ws_size,
                              hipStream_t stream) {
  const float* cloth_curr = (const float*)d_in[0];
  const float* cloth_next = (const float*)d_in[1];
  const float* obs_curr   = (const float*)d_in[2];
  const float* obs_next   = (const float*)d_in[3];
  const int*   faces      = (const int*)d_in[4];
  const int*   iter_num   = (const int*)d_in[5];
  float* out = (float*)d_out;

  // workspace: fcurr 512K @0 | fnext 1M @512K | fpack 1M @1.5M | pchunk 2M @3.5M
  char* w = (char*)d_ws;
  float4* fcurr = (float4*)(w);
  float4* fnext = (float4*)(w + 524288);
  uint4*  fpack = (uint4*)(w + 1572864);
  float2* pchunk = (float2*)(w + 3670016);

  face_precomp<<<(B_ * F_ + 127) / 128, 128, 0, stream>>>(
      obs_curr, obs_next, faces, fcurr, fnext, fpack, out);

  knn_mfma32<<<1024, 256, 0, stream>>>(cloth_curr, fpack, pchunk);

  epilogue<<<(2 * N_ + 127) / 128, 128, 0, stream>>>(
      cloth_curr, cloth_next, fcurr, fnext, pchunk, iter_num, out);
}

// Round 6
// 104.552 us; speedup vs baseline: 1.0553x; 1.0134x over previous
//
#include <hip/hip_runtime.h>
#include <math.h>

// Problem constants (fixed shapes from reference)
#define B_ 2
#define N_ 16384
#define M_ 12000
#define F_ 16384

#define P_ 128          // face partitions (argmin granularity)
#define TILE_ 128       // faces per partition
#define NCHUNK_ 8       // face chunks (knn blocks per vert-block)

typedef short bf16x8 __attribute__((ext_vector_type(8)));
typedef float f32x16 __attribute__((ext_vector_type(16)));

__device__ __host__ inline unsigned short bf16rn(float x) {
  unsigned int u = __float_as_uint(x);
  u = (u + 0x7FFFu + ((u >> 16) & 1u)) >> 16;
  return (unsigned short)u;
}
__device__ inline float bf16tof(unsigned short h) {
  return __uint_as_float(((unsigned int)h) << 16);
}

// async global->LDS, 16B per lane. LDS dest must be wave-uniform base;
// HW writes base + lane*16 (linear). Global src is per-lane.
__device__ __forceinline__ void gload_lds16(const uint4* g, uint4* l) {
  __builtin_amdgcn_global_load_lds(
      (const __attribute__((address_space(1))) void*)g,
      (__attribute__((address_space(3))) void*)l, 16, 0, 0);
}

// ---------------------------------------------------------------------------
// Kernel A: per-face precompute + out[0] zero-init.
// Round 15: wave-split. Block = 2 waves over 64 faces: wave 0 does the
// obs_curr chain (fcurr + fpack), wave 1 the obs_next chain (fnext).
// Wave-uniform branch (no divergence), no load amplification (only the 3
// face-index ints are read by both waves). Serial gather chain per wave
// halves; wave count doubles (512 -> 1024) -> better latency hiding.
//   fcurr[f] = (centroid_curr.xyz, |centroid_curr|^2)   (exact fp32 chain)
//   fnext[2f] = centroid_next, fnext[2f+1] = unit normal
//   fpack[f]  = 16 bf16 (32B): K=16 A-operand for mfma_32x32x16:
//     k0-3 {fhx,flx,fhx,flx} k4-7 {y} k8-11 {z} k12,13 {whi,wlo} k14,15 0
// ---------------------------------------------------------------------------
__global__ __launch_bounds__(128) void face_precomp(
    const float* __restrict__ obs_curr,
    const float* __restrict__ obs_next,
    const int* __restrict__ faces,
    float4* __restrict__ fcurr,
    float4* __restrict__ fnext,
    uint4* __restrict__ fpack,
    float* __restrict__ out) {
  int lane = threadIdx.x & 63;
  int half = threadIdx.x >> 6;        // 0: fcurr/fpack, 1: fnext
  int t = blockIdx.x * 64 + lane;     // face slot in [0, B*F)
  if (blockIdx.x == 0 && threadIdx.x == 0) out[0] = 0.0f;
  int b = t / F_;
  const int* fidx3 = faces + 3 * (size_t)t;
  int i0 = fidx3[0];
  int i1 = fidx3[1];
  int i2 = fidx3[2];

  if (half == 0) {
    const float* oc = obs_curr + (size_t)b * M_ * 3;
    float ax = oc[3*i0], ay = oc[3*i0+1], az = oc[3*i0+2];
    float bx = oc[3*i1], by = oc[3*i1+1], bz = oc[3*i1+2];
    float cx = oc[3*i2], cy = oc[3*i2+1], cz = oc[3*i2+2];
    float gx = (ax + bx + cx) / 3.0f;
    float gy = (ay + by + cy) / 3.0f;
    float gz = (az + bz + cz) / 3.0f;
    float w = gx*gx + gy*gy + gz*gz;
    fcurr[t] = make_float4(gx, gy, gz, w);

    float fx = -2.0f * gx, fy = -2.0f * gy, fz = -2.0f * gz;
    unsigned short fhx = bf16rn(fx), flx = bf16rn(fx - bf16tof(fhx));
    unsigned short fhy = bf16rn(fy), fly = bf16rn(fy - bf16tof(fhy));
    unsigned short fhz = bf16rn(fz), flz = bf16rn(fz - bf16tof(fhz));
    unsigned short whi = bf16rn(w),  wlo = bf16rn(w - bf16tof(whi));
    uint4 r0, r1;
    r0.x = (unsigned)fhx | ((unsigned)flx << 16);  // k0,k1
    r0.y = r0.x;                                    // k2,k3
    r0.z = (unsigned)fhy | ((unsigned)fly << 16);  // k4,k5
    r0.w = r0.z;                                    // k6,k7
    r1.x = (unsigned)fhz | ((unsigned)flz << 16);  // k8,k9
    r1.y = r1.x;                                    // k10,k11
    r1.z = (unsigned)whi | ((unsigned)wlo << 16);  // k12,k13
    r1.w = 0;                                       // k14,k15
    fpack[(size_t)t * 2 + 0] = r0;
    fpack[(size_t)t * 2 + 1] = r1;
  } else {
    const float* on = obs_next + (size_t)b * M_ * 3;
    float nax = on[3*i0], nay = on[3*i0+1], naz = on[3*i0+2];
    float nbx = on[3*i1], nby = on[3*i1+1], nbz = on[3*i1+2];
    float ncx = on[3*i2], ncy = on[3*i2+1], ncz = on[3*i2+2];
    float hx = (nax + nbx + ncx) / 3.0f;
    float hy = (nay + nby + ncy) / 3.0f;
    float hz = (naz + nbz + ncz) / 3.0f;
    float e1x = nbx - nax, e1y = nby - nay, e1z = nbz - naz;
    float e2x = ncx - nax, e2y = ncy - nay, e2z = ncz - naz;
    float crx = e1y * e2z - e1z * e2y;
    float cry = e1z * e2x - e1x * e2z;
    float crz = e1x * e2y - e1y * e2x;
    float len = sqrtf(crx*crx + cry*cry + crz*crz);
    float inv = 1.0f / (len + 1e-12f);
    fnext[2 * (size_t)t + 0] = make_float4(hx, hy, hz, 0.0f);
    fnext[2 * (size_t)t + 1] = make_float4(crx*inv, cry*inv, crz*inv, 0.0f);
  }
}

// ---------------------------------------------------------------------------
// Kernel B: 32x32x16 MFMA approximate-min pass (R2-verified form — best of
// R10/R13 variants; pair-staging regressed in R4, leave this kernel alone).
// VALU-bound ~4.5 us vs ~3.4 us min3 floor; MFMA 1.7 us hides under it.
// Chunk-level (min, argmin-partition) in registers; ONE float2 store per
// vert per chunk. LDS 4 KB partition double-buffered via global_load_lds.
// ---------------------------------------------------------------------------
__global__ __launch_bounds__(256, 4) void knn_mfma32(
    const float* __restrict__ cloth_curr,
    const uint4* __restrict__ fpack,     // 2 x uint4 per face (32 B)
    float2* __restrict__ pchunk) {       // [B][NCHUNK][N] (minval, part-idx)
  __shared__ uint4 abuf[2][256];   // 2 x 4 KB: one 128-face partition each

  int bid = blockIdx.x;            // [0, 1024)
  int s   = bid & 7;               // face chunk: [s*2048, (s+1)*2048)
  int vb  = (bid >> 3) & 63;       // 256-vert block
  int b   = bid >> 9;              // batch
  int lane = threadIdx.x & 63;
  int wid  = threadIdx.x >> 6;     // 0..3
  int h = lane >> 5;               // k-half
  int m = lane & 31;               // face-row / vert-col
  int vw = vb * 256 + wid * 64;    // wave's 64 verts

  // 2 B-frags: frag g covers verts vw + g*32 + m (col=lane&31, k=8*h+j)
  const short one = (short)0x3F80;
  bf16x8 bfrag0, bfrag1;
#pragma unroll
  for (int g = 0; g < 2; ++g) {
    const float* cp = cloth_curr + ((size_t)b * N_ + vw + g * 32 + m) * 3;
    float cxx = cp[0], cyy = cp[1], czz = cp[2];
    unsigned short chx = bf16rn(cxx), clx = bf16rn(cxx - bf16tof(chx));
    unsigned short chy = bf16rn(cyy), cly = bf16rn(cyy - bf16tof(chy));
    unsigned short chz = bf16rn(czz), clz = bf16rn(czz - bf16tof(chz));
    bf16x8 tq;
    if (h == 0) {
      tq[0] = (short)chx; tq[1] = (short)chx;
      tq[2] = (short)clx; tq[3] = (short)clx;
      tq[4] = (short)chy; tq[5] = (short)chy;
      tq[6] = (short)cly; tq[7] = (short)cly;
    } else {
      tq[0] = (short)chz; tq[1] = (short)chz;
      tq[2] = (short)clz; tq[3] = (short)clz;
      tq[4] = one; tq[5] = one;
      tq[6] = 0;   tq[7] = 0;
    }
    if (g == 0) bfrag0 = tq; else bfrag1 = tq;
  }

  f32x16 zc;
#pragma unroll
  for (int k = 0; k < 16; ++k) zc[k] = 0.0f;

  // chunk base (uint4 units): 2048 faces * 2 uint4. Partition = 256 uint4.
  const uint4* chunk = fpack + ((size_t)b * F_ + (size_t)s * 2048) * 2;

  // prologue: stage partition 0 into abuf[0] (each thread one 16B lane-slot)
  gload_lds16(chunk + wid * 64 + lane, &abuf[0][wid * 64]);
  __syncthreads();   // compiler drains vmcnt(0) before s_barrier

  // running chunk-level (min, argmin partition) per covered vert
  float rb0 = 3.4e38f, rb1 = 3.4e38f;
  int   rp0 = 0,       rp1 = 0;

  for (int part = 0; part < 16; ++part) {
    int cur = part & 1;
    // issue next partition's staging into the other buffer (no wait)
    if (part < 15)
      gload_lds16(chunk + (part + 1) * 256 + wid * 64 + lane,
                  &abuf[cur ^ 1][wid * 64]);

    float r0[8], r1[8];
#pragma unroll
    for (int k = 0; k < 8; ++k) { r0[k] = 3.4e38f; r1[k] = 3.4e38f; }

    // A-frag (face m of tile, half h) from LDS: idx (grp*64+m)*2+h and +32
    const uint4* lp = &abuf[cur][m * 2 + h];
#pragma unroll
    for (int grp = 0; grp < 2; ++grp) {   // 2 groups of 2 tiles
      uint4 a0 = lp[grp * 128];
      uint4 a1 = lp[grp * 128 + 64];
      bf16x8 av0 = __builtin_bit_cast(bf16x8, a0);
      bf16x8 av1 = __builtin_bit_cast(bf16x8, a1);
      f32x16 d00 = __builtin_amdgcn_mfma_f32_32x32x16_bf16(av0, bfrag0, zc, 0, 0, 0);
      f32x16 d01 = __builtin_amdgcn_mfma_f32_32x32x16_bf16(av0, bfrag1, zc, 0, 0, 0);
      f32x16 d10 = __builtin_amdgcn_mfma_f32_32x32x16_bf16(av1, bfrag0, zc, 0, 0, 0);
      f32x16 d11 = __builtin_amdgcn_mfma_f32_32x32x16_bf16(av1, bfrag1, zc, 0, 0, 0);
      // per-k running accumulators; min(min(a,b),c) fuses to v_min3_f32
#pragma unroll
      for (int k = 0; k < 8; ++k) {
        r0[k] = fminf(fminf(d00[k], d00[k + 8]), r0[k]);
        r0[k] = fminf(fminf(d10[k], d10[k + 8]), r0[k]);
        r1[k] = fminf(fminf(d01[k], d01[k + 8]), r1[k]);
        r1[k] = fminf(fminf(d11[k], d11[k + 8]), r1[k]);
      }
    }
    // fold 8 -> 1 per frag, merge halves
    float t0 = fminf(fminf(r0[0], r0[1]), r0[2]);
    t0 = fminf(fminf(t0, r0[3]), r0[4]);
    t0 = fminf(fminf(t0, r0[5]), r0[6]);
    float bmin0 = fminf(t0, r0[7]);
    float t1 = fminf(fminf(r1[0], r1[1]), r1[2]);
    t1 = fminf(fminf(t1, r1[3]), r1[4]);
    t1 = fminf(fminf(t1, r1[5]), r1[6]);
    float bmin1 = fminf(t1, r1[7]);
    bmin0 = fminf(bmin0, __shfl_xor(bmin0, 32, 64));
    bmin1 = fminf(bmin1, __shfl_xor(bmin1, 32, 64));

    // running argmin (strict <, ascending part => first-min-wins)
    bool u0 = bmin0 < rb0;
    rb0 = u0 ? bmin0 : rb0;
    rp0 = u0 ? part : rp0;
    bool u1 = bmin1 < rb1;
    rb1 = u1 ? bmin1 : rb1;
    rp1 = u1 ? part : rp1;

    // drain staging (vmcnt) + cross-wave LDS visibility for next partition
    if (part < 15) __syncthreads();
  }

  // one store per vert: (chunk-min, global partition index)
  float2* pout = pchunk + ((size_t)(b * NCHUNK_ + s)) * N_ + vw;
  if (lane < 32) {
    pout[lane]      = make_float2(rb0, __int_as_float(s * 16 + rp0));
    pout[32 + lane] = make_float2(rb1, __int_as_float(s * 16 + rp1));
  }
}

// ---------------------------------------------------------------------------
// Kernel C: per-(vertex,batch)-thread epilogue (R2-verified logic, R5 grid).
// Round 15: pass-2 unroll 4 -> 8 (8 outstanding 16B loads per dependent
// round instead of 4) + hoist the independent cloth_next load above the
// rescan loop. Math and selection semantics bit-identical.
// ---------------------------------------------------------------------------
__global__ __launch_bounds__(128) void epilogue(
    const float* __restrict__ cloth_curr,
    const float* __restrict__ cloth_next,
    const float4* __restrict__ fcurr,
    const float4* __restrict__ fnext,
    const float2* __restrict__ pchunk,
    const int* __restrict__ iter_num,
    float* __restrict__ out) {
  int t = blockIdx.x * 128 + threadIdx.x;  // [0, 2*N)
  int i = t >> 1;                          // vertex
  int b = t & 1;                           // batch

  // weight ramp (double to match Python scalar math)
  int it = *iter_num;
  double itc = (double)(it - 50000);
  if (itc < 0.0) itc = 0.0;
  double prog = itc / 100000.0;
  if (prog > 1.0) prog = 1.0;
  float weight = (float)(1e-3 + (5e3 - 1e-3) * prog);
  float scale = weight * 0.5f;  // weight / B

  // independent loads hoisted: cloth_curr (pass-2 query) + cloth_next (plane)
  const float* cp = cloth_curr + ((size_t)b * N_ + i) * 3;
  float m2x = -2.0f * cp[0];
  float m2y = -2.0f * cp[1];
  float m2z = -2.0f * cp[2];
  const float* np2 = cloth_next + ((size_t)b * N_ + i) * 3;
  float nx = np2[0], ny = np2[1], nz = np2[2];

  // pass 1: argmin partition over chunk minima (8 float2 loads)
  float best = 3.4e38f;
  int bp = 0;
#pragma unroll
  for (int c = 0; c < NCHUNK_; ++c) {
    float2 v = pchunk[((size_t)(b * NCHUNK_ + c)) * N_ + i];
    bool mm = v.x < best;
    best = mm ? v.x : best;
    bp = mm ? __float_as_int(v.y) : bp;
  }

  // pass 2: exact fp32 rescan of winning partition
  const float4* fpp = fcurr + (size_t)b * F_ + (size_t)bp * TILE_;
  float sbest = 3.4e38f;
  int jwin = 0;
#pragma unroll 8
  for (int j = 0; j < TILE_; ++j) {
    float4 fc = fpp[j];
    float s = fmaf(m2x, fc.x, fmaf(m2y, fc.y, fmaf(m2z, fc.z, fc.w)));
    bool u = s < sbest;
    sbest = u ? s : sbest;
    jwin = u ? j : jwin;
  }
  int fidx = bp * TILE_ + jwin;

  float4 cent = fnext[2 * ((size_t)b * F_ + fidx) + 0];
  float4 nrm  = fnext[2 * ((size_t)b * F_ + fidx) + 1];
  float dist = (nx - cent.x) * nrm.x +
               (ny - cent.y) * nrm.y +
               (nz - cent.z) * nrm.z;
  float ip = fmaxf(1e-3f - dist, 0.0f);
  float acc = ip * ip * ip * scale;

  // combine the two batches (lanes 2k / 2k+1 hold b=0 / b=1 of vertex i)
  float pair = acc + __shfl_xor(acc, 1, 64);
  if (b == 0) out[1 + i] = pair;  // per_vert

  // block-level loss partial -> one atomic per block (2 waves)
  float r = acc;
#pragma unroll
  for (int off = 32; off > 0; off >>= 1) r += __shfl_down(r, off, 64);
  __shared__ float wsum[2];
  int lane = threadIdx.x & 63;
  int w = threadIdx.x >> 6;
  if (lane == 0) wsum[w] = r;
  __syncthreads();
  if (threadIdx.x == 0)
    atomicAdd(out, wsum[0] + wsum[1]);
}

// ---------------------------------------------------------------------------
extern "C" void kernel_launch(void* const* d_in, const int* in_sizes, int n_in,
                              void* d_out, int out_size, void* d_ws, size_t ws_size,
                              hipStream_t stream) {
  const float* cloth_curr = (const float*)d_in[0];
  const float* cloth_next = (const float*)d_in[1];
  const float* obs_curr   = (const float*)d_in[2];
  const float* obs_next   = (const float*)d_in[3];
  const int*   faces      = (const int*)d_in[4];
  const int*   iter_num   = (const int*)d_in[5];
  float* out = (float*)d_out;

  // workspace: fcurr 512K @0 | fnext 1M @512K | fpack 1M @1.5M | pchunk 2M @3.5M
  char* w = (char*)d_ws;
  float4* fcurr = (float4*)(w);
  float4* fnext = (float4*)(w + 524288);
  uint4*  fpack = (uint4*)(w + 1572864);
  float2* pchunk = (float2*)(w + 3670016);

  // wave-split: 512 blocks x 128 threads, block = 2 waves over 64 faces
  face_precomp<<<(B_ * F_) / 64, 128, 0, stream>>>(
      obs_curr, obs_next, faces, fcurr, fnext, fpack, out);

  knn_mfma32<<<1024, 256, 0, stream>>>(cloth_curr, fpack, pchunk);

  epilogue<<<(2 * N_ + 127) / 128, 128, 0, stream>>>(
      cloth_curr, cloth_next, fcurr, fnext, pchunk, iter_num, out);
}